// Round 1
// baseline (42.596 us; speedup 1.0000x reference)
//
#include <hip/hip_runtime.h>
#include <cmath>

// RTMDet decode: per level, per spatial position:
//   conf = sigmoid(max_c logits), class = argmax_c logits (first occurrence),
//   box = clip([gx - l, gy - t, gx + r, gy + d], 0, 639), gx = w*step, gy = h*step.
// Output layout (flat float32 in d_out): boxes [64,8400,4] | scores [64,8400] | classes [64,8400].

constexpr int B_    = 64;
constexpr int NC    = 80;
constexpr int NTOT  = 8400;   // 6400 + 1600 + 400

__global__ __launch_bounds__(256) void decode_level_kernel(
    const float* __restrict__ cls,      // [B, 80, HW]
    const float* __restrict__ box,      // [B, 4, HW]
    float* __restrict__ oboxes,         // [B, 8400, 4]
    float* __restrict__ oscores,        // [B, 8400]
    float* __restrict__ oclasses,       // [B, 8400]
    int HW, int W, float step, int n_off, int total4)
{
    int t = blockIdx.x * blockDim.x + threadIdx.x;
    if (t >= total4) return;

    int qpi = HW >> 2;                 // quads per image
    int b   = t / qpi;
    int q   = t - b * qpi;
    int p   = q << 2;                  // first of 4 consecutive positions (same row: W % 4 == 0)
    int h   = p / W;
    int w0  = p - h * W;

    // ---- class max/argmax over 80 logits, 4 positions at a time ----
    const float* cbase = cls + (size_t)b * NC * HW + p;
    float m[4]  = {-3.4e38f, -3.4e38f, -3.4e38f, -3.4e38f};
    int   ci[4] = {0, 0, 0, 0};
    #pragma unroll 8
    for (int c = 0; c < NC; ++c) {
        float4 v = *reinterpret_cast<const float4*>(cbase + (size_t)c * HW);
        float vv[4] = {v.x, v.y, v.z, v.w};
        #pragma unroll
        for (int j = 0; j < 4; ++j) {
            if (vv[j] > m[j]) { m[j] = vv[j]; ci[j] = c; }
        }
    }

    // ---- box offsets (l, t, r, b), each a coalesced float4 ----
    const float* bbase = box + (size_t)b * 4 * HW + p;
    float4 b0 = *reinterpret_cast<const float4*>(bbase);
    float4 b1 = *reinterpret_cast<const float4*>(bbase + HW);
    float4 b2 = *reinterpret_cast<const float4*>(bbase + 2 * HW);
    float4 b3 = *reinterpret_cast<const float4*>(bbase + 3 * HW);
    float l_[4] = {b0.x, b0.y, b0.z, b0.w};
    float t_[4] = {b1.x, b1.y, b1.z, b1.w};
    float r_[4] = {b2.x, b2.y, b2.z, b2.w};
    float d_[4] = {b3.x, b3.y, b3.z, b3.w};

    float gy = h * step;
    size_t obase = (size_t)b * NTOT + n_off + p;

    float4 obox[4];
    float  osc[4], ocl[4];
    #pragma unroll
    for (int j = 0; j < 4; ++j) {
        float gx = (float)(w0 + j) * step;
        float x1 = fminf(fmaxf(gx - l_[j], 0.0f), 639.0f);
        float y1 = fminf(fmaxf(gy - t_[j], 0.0f), 639.0f);
        float x2 = fminf(fmaxf(gx + r_[j], 0.0f), 639.0f);
        float y2 = fminf(fmaxf(gy + d_[j], 0.0f), 639.0f);
        obox[j] = make_float4(x1, y1, x2, y2);
        osc[j]  = 1.0f / (1.0f + expf(-m[j]));
        ocl[j]  = (float)ci[j];
    }

    float4* ob = reinterpret_cast<float4*>(oboxes + obase * 4);
    ob[0] = obox[0]; ob[1] = obox[1]; ob[2] = obox[2]; ob[3] = obox[3];
    *reinterpret_cast<float4*>(oscores  + obase) = make_float4(osc[0], osc[1], osc[2], osc[3]);
    *reinterpret_cast<float4*>(oclasses + obase) = make_float4(ocl[0], ocl[1], ocl[2], ocl[3]);
}

extern "C" void kernel_launch(void* const* d_in, const int* in_sizes, int n_in,
                              void* d_out, int out_size, void* d_ws, size_t ws_size,
                              hipStream_t stream) {
    const float* cls0 = (const float*)d_in[0];
    const float* box0 = (const float*)d_in[1];
    const float* cls1 = (const float*)d_in[2];
    const float* box1 = (const float*)d_in[3];
    const float* cls2 = (const float*)d_in[4];
    const float* box2 = (const float*)d_in[5];

    float* oboxes   = (float*)d_out;
    float* oscores  = oboxes  + (size_t)B_ * NTOT * 4;
    float* oclasses = oscores + (size_t)B_ * NTOT;

    auto launch = [&](const float* c, const float* bx, int HW, int W, float step, int noff) {
        int total4 = B_ * (HW / 4);
        int blocks = (total4 + 255) / 256;
        decode_level_kernel<<<blocks, 256, 0, stream>>>(c, bx, oboxes, oscores, oclasses,
                                                        HW, W, step, noff, total4);
    };
    launch(cls0, box0, 80 * 80, 80,  8.0f,    0);
    launch(cls1, box1, 40 * 40, 40, 16.0f, 6400);
    launch(cls2, box2, 20 * 20, 20, 32.0f, 8000);
}

// Round 2
// 35.088 us; speedup vs baseline: 1.2140x; 1.2140x over previous
//
#include <hip/hip_runtime.h>
#include <cmath>

// RTMDet decode, fused single-kernel version.
// Per spatial position: conf = sigmoid(max_c logit), class = argmax_c logit (first occurrence),
// box = clip([gx-l, gy-t, gx+r, gy+d], 0, 639), gx = w*step, gy = h*step.
// Output layout (flat float32 in d_out): boxes [64,8400,4] | scores [64,8400] | classes [64,8400].
//
// Decomposition (one launch, 525 blocks x 256 threads):
//   blocks [0,400)   -> level 0 (80x80, step 8)
//   blocks [400,500) -> level 1 (40x40, step 16)
//   blocks [500,525) -> level 2 (20x20, step 32)
// Level boundaries fall exactly on block boundaries, so no intra-block divergence.
//
// cls argmax: thread <-> quad of 4 consecutive positions -> float4 loads over 80 classes
//             (the 172 MB that dominates traffic; perfectly coalesced 16B/lane).
// boxes:      thread <-> 4 lane-contiguous positions (tid + k*256) -> 16 coalesced scalar
//             loads, 4 perfectly coalesced float4 stores (fixes the 64B-stride scatter).

constexpr int B_   = 64;
constexpr int NC   = 80;
constexpr int NTOT = 8400;   // 6400 + 1600 + 400

template<int HW, int W, int STEP, int NOFF>
__device__ __forceinline__ void decode_level(
    const float* __restrict__ cls, const float* __restrict__ box,
    float* __restrict__ oboxes, float* __restrict__ oscores, float* __restrict__ oclasses,
    int lbid, int tid)
{
    constexpr int QPI = HW / 4;                 // quads per image

    // ---------- class max/argmax: quad (4 consecutive positions) per thread ----------
    int t  = lbid * 256 + tid;                  // quad index in [0, 64*QPI)
    int b  = t / QPI;                           // compile-time QPI -> magic mul
    int p  = (t - b * QPI) << 2;                // first of 4 consecutive positions

    const float* cbase = cls + (size_t)b * NC * HW + p;
    float m[4]  = {-3.4e38f, -3.4e38f, -3.4e38f, -3.4e38f};
    int   ci[4] = {0, 0, 0, 0};
    #pragma unroll 8
    for (int c = 0; c < NC; ++c) {
        float4 v = *reinterpret_cast<const float4*>(cbase + (size_t)c * HW);
        float vv[4] = {v.x, v.y, v.z, v.w};
        #pragma unroll
        for (int j = 0; j < 4; ++j) {
            if (vv[j] > m[j]) { m[j] = vv[j]; ci[j] = c; }   // strict > : first occurrence
        }
    }

    size_t obase = (size_t)b * NTOT + NOFF + p;
    float4 osc, ocl;
    osc.x = 1.0f / (1.0f + __expf(-m[0]));
    osc.y = 1.0f / (1.0f + __expf(-m[1]));
    osc.z = 1.0f / (1.0f + __expf(-m[2]));
    osc.w = 1.0f / (1.0f + __expf(-m[3]));
    ocl.x = (float)ci[0]; ocl.y = (float)ci[1]; ocl.z = (float)ci[2]; ocl.w = (float)ci[3];
    *reinterpret_cast<float4*>(oscores  + obase) = osc;     // lanes contiguous -> coalesced
    *reinterpret_cast<float4*>(oclasses + obase) = ocl;

    // ---------- boxes: 4 lane-contiguous positions per thread ----------
    int base = lbid * 1024;                     // level-local first position of this block
    #pragma unroll
    for (int k = 0; k < 4; ++k) {
        int P  = base + tid + (k << 8);         // level-local element pos in [0, 64*HW)
        int bb = P / HW;                        // compile-time HW -> magic mul
        int pp = P - bb * HW;
        int hh = pp / W;                        // compile-time W -> magic mul
        int ww = pp - hh * W;

        const float* bbase = box + (size_t)bb * 4 * HW + pp;
        float l  = bbase[0];                    // each: lanes at consecutive pp -> coalesced
        float tt = bbase[HW];
        float r  = bbase[2 * HW];
        float dd = bbase[3 * HW];

        float gx = (float)(ww * STEP);
        float gy = (float)(hh * STEP);
        float4 o;
        o.x = fminf(fmaxf(gx - l,  0.0f), 639.0f);
        o.y = fminf(fmaxf(gy - tt, 0.0f), 639.0f);
        o.z = fminf(fmaxf(gx + r,  0.0f), 639.0f);
        o.w = fminf(fmaxf(gy + dd, 0.0f), 639.0f);

        size_t ob = (size_t)bb * NTOT + NOFF + pp;
        *reinterpret_cast<float4*>(oboxes + ob * 4) = o;    // lanes contiguous -> coalesced
    }
}

__global__ __launch_bounds__(256) void rtmdet_decode_fused(
    const float* __restrict__ cls0, const float* __restrict__ box0,
    const float* __restrict__ cls1, const float* __restrict__ box1,
    const float* __restrict__ cls2, const float* __restrict__ box2,
    float* __restrict__ oboxes, float* __restrict__ oscores, float* __restrict__ oclasses)
{
    int bid = blockIdx.x;
    int tid = threadIdx.x;
    if (bid < 400) {
        decode_level<6400, 80,  8,    0>(cls0, box0, oboxes, oscores, oclasses, bid,       tid);
    } else if (bid < 500) {
        decode_level<1600, 40, 16, 6400>(cls1, box1, oboxes, oscores, oclasses, bid - 400, tid);
    } else {
        decode_level< 400, 20, 32, 8000>(cls2, box2, oboxes, oscores, oclasses, bid - 500, tid);
    }
}

extern "C" void kernel_launch(void* const* d_in, const int* in_sizes, int n_in,
                              void* d_out, int out_size, void* d_ws, size_t ws_size,
                              hipStream_t stream) {
    const float* cls0 = (const float*)d_in[0];
    const float* box0 = (const float*)d_in[1];
    const float* cls1 = (const float*)d_in[2];
    const float* box1 = (const float*)d_in[3];
    const float* cls2 = (const float*)d_in[4];
    const float* box2 = (const float*)d_in[5];

    float* oboxes   = (float*)d_out;
    float* oscores  = oboxes  + (size_t)B_ * NTOT * 4;
    float* oclasses = oscores + (size_t)B_ * NTOT;

    rtmdet_decode_fused<<<525, 256, 0, stream>>>(cls0, box0, cls1, box1, cls2, box2,
                                                 oboxes, oscores, oclasses);
}